// Round 1
// baseline (748.269 us; speedup 1.0000x reference)
//
#include <hip/hip_runtime.h>
#include <stdint.h>

#define TOKENS 65536
#define KDIM 1024
#define NDIM 1024
#define MROWS 65664            // TOKENS + 128, multiple of 128
#define ROWTILES 513           // MROWS / 128

using short8 = __attribute__((ext_vector_type(8))) short;
using f32x4  = __attribute__((ext_vector_type(4))) float;

// async global->LDS, 16B per lane; LDS dest must be wave-uniform base (+lane*16 in HW)
#define ASYNC_COPY16(g, l) __builtin_amdgcn_global_load_lds( \
    (const __attribute__((address_space(1))) void*)(g),      \
    (__attribute__((address_space(3))) void*)(l), 16, 0, 0)

__device__ __forceinline__ short f2bf(float f) {
    union { float f; unsigned u; } c; c.f = f;
    unsigned r = c.u + 0x7FFFu + ((c.u >> 16) & 1u);   // round-to-nearest-even
    return (short)(r >> 16);
}

// ---------- mask format detection: 0=int32{0,1}, 1=bytes, 2=float32 ----------
__global__ __launch_bounds__(256) void detect_mask_fmt(const unsigned* __restrict__ mask,
                                                       int* __restrict__ hdr) {
    int mode = 0;
    for (int i = threadIdx.x; i < 16384; i += 256) {
        unsigned w = mask[i];
        if (w == 0x3F800000u) { mode = 2; break; }   // float 1.0 pattern
        if (w > 1u) mode = 1;                        // packed bytes
    }
    if (mode) atomicMax(&hdr[2], mode);
}

__device__ __forceinline__ bool read_mask(const void* mask, int fmt, int t) {
    if (fmt == 2) return ((const float*)mask)[t] != 0.0f;
    if (fmt == 1) return ((const unsigned char*)mask)[t] != 0;
    return ((const int*)mask)[t] != 0;
}

// ---------- slot assignment: visual ascending from 0, text descending from MROWS-1 ----------
__global__ __launch_bounds__(256) void route_assign(const void* __restrict__ mask,
                                                    int* __restrict__ rowmap,
                                                    int* __restrict__ slotmap,
                                                    int* __restrict__ hdr) {
    const int tid  = threadIdx.x;
    const int lane = tid & 63;
    const int wid  = tid >> 6;
    const int t    = blockIdx.x * 256 + tid;
    const int fmt  = hdr[2];
    const bool m   = read_mask(mask, fmt, t);

    unsigned long long bal = __ballot(m);
    int vpre = __popcll(bal & ((1ull << lane) - 1ull));
    int vcnt = __popcll(bal);
    int tpre = lane - vpre;
    int tcnt = 64 - vcnt;

    __shared__ int cv[4], ct[4], ov[4], ot[4];
    __shared__ int bv, bt;
    if (lane == 0) { cv[wid] = vcnt; ct[wid] = tcnt; }
    __syncthreads();
    if (tid == 0) {
        int sv = 0, st = 0;
        for (int w = 0; w < 4; ++w) { ov[w] = sv; sv += cv[w]; ot[w] = st; st += ct[w]; }
        bv = atomicAdd(&hdr[0], sv);   // hdr[0] ends as Mv
        bt = atomicAdd(&hdr[1], st);
    }
    __syncthreads();
    int slot = m ? (bv + ov[wid] + vpre)
                 : (MROWS - 1 - (bt + ot[wid] + tpre));
    rowmap[slot] = t;
    slotmap[t] = slot;
}

// ---------- gather fp32 row -> bf16 compact row (1 wave per token) ----------
__global__ __launch_bounds__(256) void gather_convert(const float* __restrict__ x,
                                                      const int* __restrict__ slotmap,
                                                      short* __restrict__ Abuf) {
    const int lane = threadIdx.x & 63;
    const int t    = blockIdx.x * 4 + (threadIdx.x >> 6);
    const int slot = slotmap[t];
    const float* src = x + (size_t)t * KDIM;
    short* dst = Abuf + (size_t)slot * KDIM;
#pragma unroll
    for (int p = 0; p < 4; ++p) {
        int k = p * 256 + lane * 4;
        float4 v = *(const float4*)(src + k);
        short4 o;
        o.x = f2bf(v.x); o.y = f2bf(v.y); o.z = f2bf(v.z); o.w = f2bf(v.w);
        *(short4*)(dst + k) = o;
    }
}

// ---------- weights fp32 -> bf16 ----------
__global__ __launch_bounds__(256) void convert_weights(const float* __restrict__ wv,
                                                       const float* __restrict__ wt,
                                                       short* __restrict__ ovp,
                                                       short* __restrict__ otp) {
    int i = (blockIdx.x * 256 + threadIdx.x) * 4;
    const float* src; short* dst; int off;
    if (i < NDIM * KDIM) { src = wv; dst = ovp; off = i; }
    else                 { src = wt; dst = otp; off = i - NDIM * KDIM; }
    float4 v = *(const float4*)(src + off);
    short4 o;
    o.x = f2bf(v.x); o.y = f2bf(v.y); o.z = f2bf(v.z); o.w = f2bf(v.w);
    *(short4*)(dst + off) = o;
}

// ---------- routed GEMM: out[token, n] = sum_k A[row,k] * Wsel[n,k] ----------
// 128x128 tile, BK=32, 4 waves, each wave 4x4 frags of mfma_f32_16x16x32_bf16
__global__ __launch_bounds__(256) void gemm_routed(const short* __restrict__ Abuf,
                                                   const short* __restrict__ Wv,
                                                   const short* __restrict__ Wt,
                                                   const int* __restrict__ rowmap,
                                                   const int* __restrict__ hdr,
                                                   float* __restrict__ out) {
    __shared__ __align__(16) short As[128 * 32];   // 8 KB, row-major [128][32]
    __shared__ __align__(16) short Bs[128 * 32];   // 8 KB
    __shared__ int rmap_s[128];

    const int Mv = hdr[0];
    const int r0 = blockIdx.y * 128;
    if (r0 == Mv) return;                          // gap-only tile (uniform exit)
    const int n0 = blockIdx.x * 128;
    const short* Wsel = (r0 < Mv) ? Wv : Wt;       // tiles never straddle: gap is exactly 128 rows

    const int tid  = threadIdx.x;
    const int lane = tid & 63;
    const int wvid = tid >> 6;

    if (tid < 128) rmap_s[tid] = rowmap[r0 + tid];

    // staging coords: thread covers (row = wvid*16 + lane/4, koct = (lane&3)*8) per 64-row round
    const int srow = wvid * 16 + (lane >> 2);
    const int koct = (lane & 3) * 8;
    const short* aP = Abuf + (size_t)(r0 + srow) * KDIM + koct;
    const short* bP = Wsel + (size_t)(n0 + srow) * KDIM + koct;
    char* lA = (char*)As + wvid * 1024;            // wave-uniform LDS bases
    char* lB = (char*)Bs + wvid * 1024;

    f32x4 acc[4][4];
#pragma unroll
    for (int i = 0; i < 4; ++i)
#pragma unroll
        for (int j = 0; j < 4; ++j) acc[i][j] = f32x4{0.f, 0.f, 0.f, 0.f};

    const int wm = (wvid & 1) * 64;
    const int wn = (wvid >> 1) * 64;
    const short* aF = As + (wm + (lane & 15)) * 32 + (lane >> 4) * 8;
    const short* bF = Bs + (wn + (lane & 15)) * 32 + (lane >> 4) * 8;

    for (int kt = 0; kt < KDIM / 32; ++kt) {
        const int k0 = kt * 32;
        __syncthreads();                           // prior compute done before overwrite
        ASYNC_COPY16(aP + k0,             lA);
        ASYNC_COPY16(aP + 64 * KDIM + k0, lA + 4096);
        ASYNC_COPY16(bP + k0,             lB);
        ASYNC_COPY16(bP + 64 * KDIM + k0, lB + 4096);
        __syncthreads();                           // vmcnt(0) drain -> staged data visible

        short8 af[4], bf[4];
#pragma unroll
        for (int mt = 0; mt < 4; ++mt) af[mt] = *(const short8*)(aF + mt * 16 * 32);
#pragma unroll
        for (int nt = 0; nt < 4; ++nt) bf[nt] = *(const short8*)(bF + nt * 16 * 32);
#pragma unroll
        for (int mt = 0; mt < 4; ++mt)
#pragma unroll
            for (int nt = 0; nt < 4; ++nt)
                acc[mt][nt] = __builtin_amdgcn_mfma_f32_16x16x32_bf16(
                    af[mt], bf[nt], acc[mt][nt], 0, 0, 0);
    }

    // epilogue: C/D layout col=lane&15, row=(lane>>4)*4+reg; scatter by rowmap
    const int col = n0 + wn + (lane & 15);
#pragma unroll
    for (int mt = 0; mt < 4; ++mt) {
        int rb = wm + mt * 16 + ((lane >> 4) << 2);
#pragma unroll
        for (int i = 0; i < 4; ++i) {
            int token = rmap_s[rb + i];
            if (token < 0) continue;               // padding row
            float* orow = out + (size_t)token * NDIM + col;
            orow[0]  = acc[mt][0][i];
            orow[16] = acc[mt][1][i];
            orow[32] = acc[mt][2][i];
            orow[48] = acc[mt][3][i];
        }
    }
}

// ---------- fp32 fallback (only if workspace too small) ----------
__global__ __launch_bounds__(256) void fallback_matvec(const float* __restrict__ x,
                                                       const void* __restrict__ mask,
                                                       const float* __restrict__ wv,
                                                       const float* __restrict__ wt,
                                                       const int* __restrict__ hdr,
                                                       float* __restrict__ out) {
    __shared__ float xs[KDIM];
    const int t = blockIdx.x;
    const int fmt = hdr[2];
    const bool m = read_mask(mask, fmt, t);
    const float* w = m ? wv : wt;
    const float* src = x + (size_t)t * KDIM;
    for (int k = threadIdx.x; k < KDIM; k += 256) xs[k] = src[k];
    __syncthreads();
    for (int n = threadIdx.x; n < NDIM; n += 256) {
        const float* wr = w + (size_t)n * KDIM;
        float s = 0.f;
        for (int k = 0; k < KDIM; ++k) s += xs[k] * wr[k];
        out[(size_t)t * NDIM + n] = s;
    }
}

extern "C" void kernel_launch(void* const* d_in, const int* in_sizes, int n_in,
                              void* d_out, int out_size, void* d_ws, size_t ws_size,
                              hipStream_t stream) {
    const float* x    = (const float*)d_in[0];
    const void*  mask = d_in[1];
    const float* w_v  = (const float*)d_in[2];
    const float* w_t  = (const float*)d_in[3];
    float* out = (float*)d_out;

    char* ws = (char*)d_ws;
    // workspace layout (all 16B-aligned offsets)
    int*   hdr     = (int*)ws;                      // [0]=cnt_v [1]=cnt_t [2]=mask fmt
    int*   rowmap  = (int*)(ws + 4096);             // MROWS ints
    int*   slotmap = (int*)(ws + 270336);           // TOKENS ints
    short* wvb     = (short*)(ws + 532480);         // 2 MB
    short* wtb     = (short*)(ws + 2629632);        // 2 MB
    short* Abuf    = (short*)(ws + 4726784);        // MROWS*1024 bf16 = 134.5 MB
    const size_t need = 4726784ull + (size_t)MROWS * KDIM * sizeof(short);

    if (ws_size >= need) {
        hipMemsetAsync(hdr, 0, 4096, stream);
        hipMemsetAsync(rowmap, 0xFF, MROWS * sizeof(int), stream);   // -1 sentinels
        detect_mask_fmt<<<1, 256, 0, stream>>>((const unsigned*)mask, hdr);
        route_assign<<<TOKENS / 256, 256, 0, stream>>>(mask, rowmap, slotmap, hdr);
        gather_convert<<<TOKENS / 4, 256, 0, stream>>>(x, slotmap, Abuf);
        convert_weights<<<(2 * NDIM * KDIM) / (256 * 4), 256, 0, stream>>>(w_v, w_t, wvb, wtb);
        gemm_routed<<<dim3(8, ROWTILES), 256, 0, stream>>>(Abuf, wvb, wtb, rowmap, hdr, out);
    } else {
        hipMemsetAsync(hdr, 0, 16, stream);
        detect_mask_fmt<<<1, 256, 0, stream>>>((const unsigned*)mask, hdr);
        fallback_matvec<<<TOKENS, 256, 0, stream>>>(x, mask, w_v, w_t, hdr, out);
    }
}